// Round 10
// baseline (134.760 us; speedup 1.0000x reference)
//
#include <hip/hip_runtime.h>
#include <hip/hip_bf16.h>

// Head: k/q/v projection + causal softmax attention, single head.
// B=8, T=4096, C=1024, H=64. All inputs fp32; output fp32.
//   k0: wT[n][k] bf16 transpose of [Wq|Wk|Wv]  (q cols pre-scaled by 0.125*log2e)
//   k1: qkv v4: global_load_lds staging (HW prefetch, un-sinkable) + counted
//       vmcnt(5) + 2 barriers/phase. 512 blocks x 512 thd: 8 waves = 4 row-
//       groups x 2 K-halves; 16 phases of K=32; LDS merge of K-halves.
//       R8/R9 lesson: compiler sinks source-level register prefetches
//       (VGPR 68/52 < declared live set) -> serial HBM latency per phase.
//   k2: flash attention (R8-verified): 32x32x16 swapped-operand, lane-local
//       softmax, shfl_xor(32) exchanges, paired (ti,127-ti) tiles, 4-way KV
//       split, LDS merge.

#define HS 64
#define NE 1024
#define NB 8
#define TS 4096
#define NROW (NB * TS)  // 32768

typedef __attribute__((ext_vector_type(4)))  float f32x4;
typedef __attribute__((ext_vector_type(16))) float f32x16;
typedef __attribute__((ext_vector_type(8)))  short s16x8;   // bf16x8 MFMA fragment
typedef __attribute__((ext_vector_type(4)))  float vfloat4;

__device__ __forceinline__ unsigned short f2bf(float x) {
  return __builtin_bit_cast(unsigned short, __float2bfloat16(x));
}
__device__ __forceinline__ unsigned pkbf(float lo, float hi) {
  return (unsigned)f2bf(lo) | ((unsigned)f2bf(hi) << 16);
}

union ABFrag { s16x8 v; unsigned d[4]; };

__device__ __forceinline__ void gl_lds16(const unsigned short* g, unsigned char* l) {
  __builtin_amdgcn_global_load_lds(
      (const __attribute__((address_space(1))) unsigned int*)(g),
      (__attribute__((address_space(3))) unsigned int*)(l), 16, 0, 0);
}

// ---------------- kernel 0: weight transpose+cast ----------------
__global__ __launch_bounds__(256) void wt_kernel(const float* __restrict__ Wk,
                                                 const float* __restrict__ Wq,
                                                 const float* __restrict__ Wv,
                                                 unsigned short* __restrict__ wT) {
  int gid = blockIdx.x * 256 + threadIdx.x;   // 0..196607
  int n = gid >> 10, k = gid & 1023;
  const float* W = (n < 64) ? Wq : (n < 128) ? Wk : Wv;
  float s = (n < 64) ? 0.18033688011112042f : 1.0f;  // 0.125 * log2(e)
  wT[gid] = f2bf(W[k * 64 + (n & 63)] * s);
}

// ---------------- kernel 1: fused QKV projection v4 ----------------
// Block 512 thd = 8 waves: wave = (r, kh), r in 0..3 (16-row group), kh in
// 0..1 (K half of 512). Per kh: 2 LDS buffers of 12288 B; buffer = 768 slots
// of 16 B; slot s = 192*g + n holds wT[n][k0 + 32*chunk + 8g .. +7].
// Stage: the 4 r-waves of a kh each issue 3 global_load_lds (slots
// p*256 + r*64 + lane). Read: lane (g,nn) reads slot 192g+16i+nn (b128,
// uniform 8 dwords/bank = conflict-free minimum).
// Phase: vmcnt(5) -> barrier -> ds_read+MFMA -> barrier -> issue c+2 cluster
// {3 gload_lds, 2 x-loads}. vmcnt never 0 until the peeled last phase.
__global__ __launch_bounds__(512, 4) void qkv_kernel(const float* __restrict__ x,
                                                     const unsigned short* __restrict__ wT,
                                                     unsigned short* __restrict__ q_ws,
                                                     unsigned short* __restrict__ k_ws,
                                                     unsigned short* __restrict__ vT) {
  __shared__ __align__(16) unsigned char smem[49152];
  const int wv = threadIdx.x >> 6, lane = threadIdx.x & 63;
  const int r = wv >> 1, kh = wv & 1;
  const int g = lane >> 4, nn = lane & 15;
  const int m0 = blockIdx.x * 64 + r * 16;
  const int k0 = kh * 512;

  f32x4 acc[12];
#pragma unroll
  for (int i = 0; i < 12; ++i) acc[i] = f32x4{0.f, 0.f, 0.f, 0.f};

  const float* xr = x + (size_t)(m0 + nn) * NE + k0 + 8 * g;

  // staging source pointers (per lane): parts p=0..2, slot s = p*256+r*64+lane
  const int s0i = 0 * 256 + r * 64 + lane;
  const int s1i = 1 * 256 + r * 64 + lane;
  const int s2i = 2 * 256 + r * 64 + lane;
  const unsigned short* sp0 = wT + (size_t)(s0i % 192) * NE + k0 + (s0i / 192) * 8;
  const unsigned short* sp1 = wT + (size_t)(s1i % 192) * NE + k0 + (s1i / 192) * 8;
  const unsigned short* sp2 = wT + (size_t)(s2i % 192) * NE + k0 + (s2i / 192) * 8;

  unsigned char* khbase = smem + kh * 24576;

  vfloat4 xA0, xA1, xB0, xB1;

  // ---- prologue: cluster(chunk0)->buf0, cluster(chunk1)->buf1 ----
  gl_lds16(sp0, khbase + r * 1024);
  gl_lds16(sp1, khbase + 4096 + r * 1024);
  gl_lds16(sp2, khbase + 8192 + r * 1024);
  xA0 = ((const vfloat4*)(xr))[0];
  xA1 = ((const vfloat4*)(xr))[1];
  __builtin_amdgcn_sched_barrier(0);
  gl_lds16(sp0 + 32, khbase + 12288 + r * 1024);
  gl_lds16(sp1 + 32, khbase + 12288 + 4096 + r * 1024);
  gl_lds16(sp2 + 32, khbase + 12288 + 8192 + r * 1024);
  xB0 = ((const vfloat4*)(xr + 32))[0];
  xB1 = ((const vfloat4*)(xr + 32))[1];
  __builtin_amdgcn_sched_barrier(0);

#define PHASE(C, VM, DOISS)                                                    \
  {                                                                            \
    asm volatile("s_waitcnt vmcnt(" #VM ")" ::: "memory");                     \
    __builtin_amdgcn_s_barrier();                                              \
    __builtin_amdgcn_sched_barrier(0);                                         \
    ABFrag af;                                                                 \
    {                                                                          \
      vfloat4 va, vb;                                                          \
      if (((C) & 1) == 0) { va = xA0; vb = xA1; } else { va = xB0; vb = xB1; } \
      af.d[0] = pkbf(va.x, va.y); af.d[1] = pkbf(va.z, va.w);                  \
      af.d[2] = pkbf(vb.x, vb.y); af.d[3] = pkbf(vb.z, vb.w);                  \
    }                                                                          \
    const unsigned char* rb_ =                                                 \
        khbase + ((C) & 1) * 12288 + (size_t)(g * 192 + nn) * 16;              \
    _Pragma("unroll")                                                          \
    for (int i = 0; i < 12; ++i) {                                             \
      const s16x8 bf = *(const s16x8*)(rb_ + i * 256);                         \
      acc[i] = __builtin_amdgcn_mfma_f32_16x16x32_bf16(af.v, bf, acc[i], 0, 0, 0); \
    }                                                                          \
    __builtin_amdgcn_sched_barrier(0);                                         \
    __builtin_amdgcn_s_barrier();                                              \
    __builtin_amdgcn_sched_barrier(0);                                         \
    if (DOISS) {                                                               \
      const int cc_ = (C) + 2;                                                 \
      unsigned char* db_ = khbase + ((C) & 1) * 12288;                         \
      gl_lds16(sp0 + cc_ * 32, db_ + r * 1024);                                \
      gl_lds16(sp1 + cc_ * 32, db_ + 4096 + r * 1024);                         \
      gl_lds16(sp2 + cc_ * 32, db_ + 8192 + r * 1024);                         \
      if (((C) & 1) == 0) {                                                    \
        xA0 = ((const vfloat4*)(xr + cc_ * 32))[0];                            \
        xA1 = ((const vfloat4*)(xr + cc_ * 32))[1];                            \
      } else {                                                                 \
        xB0 = ((const vfloat4*)(xr + cc_ * 32))[0];                            \
        xB1 = ((const vfloat4*)(xr + cc_ * 32))[1];                            \
      }                                                                        \
    }                                                                          \
    __builtin_amdgcn_sched_barrier(0);                                         \
  }

#pragma unroll
  for (int c = 0; c < 14; ++c) PHASE(c, 5, 1)
  PHASE(14, 5, 0)
  PHASE(15, 0, 0)
#undef PHASE

  // ---- merge K halves: kh=1 writes, kh=0 adds + stores ----
  __syncthreads();
  float* msm = (float*)smem;
  const int mofs = (r * 64 + lane) * 48;
  if (kh == 1) {
#pragma unroll
    for (int i = 0; i < 12; ++i) *(f32x4*)&msm[mofs + i * 4] = acc[i];
  }
  __syncthreads();
  if (kh == 0) {
#pragma unroll
    for (int i = 0; i < 12; ++i) acc[i] += *(const f32x4*)&msm[mofs + i * 4];
    const int rbase = m0 + 4 * g;
#pragma unroll
    for (int i = 0; i < 12; ++i) {
      const int c = 16 * i + nn;
#pragma unroll
      for (int j = 0; j < 4; ++j) {
        const int rr = rbase + j;
        const unsigned short h = f2bf(acc[i][j]);
        if (c < 64) {
          q_ws[(size_t)rr * HS + c] = h;
        } else if (c < 128) {
          k_ws[(size_t)rr * HS + (c - 64)] = h;
        } else {
          const int b = rr >> 12, t = rr & 4095;
          vT[((size_t)(b * HS + (c - 128))) * TS + t] = h;
        }
      }
    }
  }
}

// ---------------- kernel 2: causal flash attention, 32x32 lane-local -------
// S^T(32kv x 32q) = sum_kk mfma32x32x16(K-frag, Q^T-frag). Lane (qi,hi) holds
// st_[r] = S^T[kv=(r&3)+8*(r>>2)+4hi][q=qi]; the other 16 kv live in lane^32.
// Reduces and P^T B-frag assembly use __shfl_xor(...,32).
#define TILE32(S0, DIAG, QF, M_RUN, L_RUN, O)                                  \
  {                                                                            \
    const int s0_ = (S0);                                                      \
    const unsigned short* kr_ = kptr + (size_t)(s0_ + qi) * HS + hi8;          \
    const s16x8 ka0_ = *(const s16x8*)(kr_);                                   \
    const s16x8 ka1_ = *(const s16x8*)(kr_ + 16);                              \
    const s16x8 ka2_ = *(const s16x8*)(kr_ + 32);                              \
    const s16x8 ka3_ = *(const s16x8*)(kr_ + 48);                              \
    const unsigned short* vr0_ = vptr + (size_t)qi * TS + s0_ + hi8;           \
    const unsigned short* vr1_ = vptr + (size_t)(32 + qi) * TS + s0_ + hi8;    \
    f32x16 st_;                                                                \
    _Pragma("unroll") for (int r = 0; r < 16; ++r) st_[r] = 0.f;               \
    st_ = __builtin_amdgcn_mfma_f32_32x32x16_bf16(ka0_, QF[0], st_, 0, 0, 0);  \
    st_ = __builtin_amdgcn_mfma_f32_32x32x16_bf16(ka1_, QF[1], st_, 0, 0, 0);  \
    st_ = __builtin_amdgcn_mfma_f32_32x32x16_bf16(ka2_, QF[2], st_, 0, 0, 0);  \
    st_ = __builtin_amdgcn_mfma_f32_32x32x16_bf16(ka3_, QF[3], st_, 0, 0, 0);  \
    if (DIAG) {                                                                \
      _Pragma("unroll") for (int r = 0; r < 16; ++r) {                         \
        const int kvl_ = (r & 3) + 8 * (r >> 2) + hi4;                         \
        if (kvl_ > qi) st_[r] = -1e30f;                                        \
      }                                                                        \
    }                                                                          \
    float mx_ =                                                                \
      fmaxf(fmaxf(fmaxf(fmaxf(st_[0], st_[1]), fmaxf(st_[2], st_[3])),         \
                  fmaxf(fmaxf(st_[4], st_[5]), fmaxf(st_[6], st_[7]))),        \
            fmaxf(fmaxf(fmaxf(st_[8], st_[9]), fmaxf(st_[10], st_[11])),       \
                  fmaxf(fmaxf(st_[12], st_[13]), fmaxf(st_[14], st_[15]))));   \
    mx_ = fmaxf(mx_, __shfl_xor(mx_, 32, 64));                                 \
    const float mn_ = fmaxf(M_RUN, mx_);                                       \
    if (__ballot(mn_ > M_RUN)) {                                               \
      const float fs_ = __builtin_amdgcn_exp2f(M_RUN - mn_);                   \
      _Pragma("unroll") for (int r = 0; r < 16; ++r) {                         \
        O[0][r] *= fs_; O[1][r] *= fs_;                                        \
      }                                                                        \
      L_RUN *= fs_;                                                            \
      M_RUN = mn_;                                                             \
    }                                                                          \
    float p_[16];                                                              \
    _Pragma("unroll") for (int r = 0; r < 16; ++r)                             \
      p_[r] = __builtin_amdgcn_exp2f(st_[r] - M_RUN);                          \
    float sm_ = ((p_[0] + p_[1]) + (p_[2] + p_[3])) +                          \
                ((p_[4] + p_[5]) + (p_[6] + p_[7]));                           \
    sm_ += ((p_[8] + p_[9]) + (p_[10] + p_[11])) +                             \
           ((p_[12] + p_[13]) + (p_[14] + p_[15]));                            \
    sm_ += __shfl_xor(sm_, 32, 64);                                            \
    L_RUN += sm_;                                                              \
    const unsigned q01_ = pkbf(p_[0], p_[1]),   q23_ = pkbf(p_[2], p_[3]);     \
    const unsigned q45_ = pkbf(p_[4], p_[5]),   q67_ = pkbf(p_[6], p_[7]);     \
    const unsigned q89_ = pkbf(p_[8], p_[9]),   qab_ = pkbf(p_[10], p_[11]);   \
    const unsigned qcd_ = pkbf(p_[12], p_[13]), qef_ = pkbf(p_[14], p_[15]);   \
    const unsigned t01_ = (unsigned)__shfl_xor((int)q01_, 32, 64);             \
    const unsigned t23_ = (unsigned)__shfl_xor((int)q23_, 32, 64);             \
    const unsigned t45_ = (unsigned)__shfl_xor((int)q45_, 32, 64);             \
    const unsigned t67_ = (unsigned)__shfl_xor((int)q67_, 32, 64);             \
    const unsigned t89_ = (unsigned)__shfl_xor((int)q89_, 32, 64);             \
    const unsigned tab_ = (unsigned)__shfl_xor((int)qab_, 32, 64);             \
    const unsigned tcd_ = (unsigned)__shfl_xor((int)qcd_, 32, 64);             \
    const unsigned tef_ = (unsigned)__shfl_xor((int)qef_, 32, 64);             \
    ABFrag pf0_, pf1_;                                                         \
    pf0_.d[0] = hi ? t45_ : q01_;                                              \
    pf0_.d[1] = hi ? t67_ : q23_;                                              \
    pf0_.d[2] = hi ? q45_ : t01_;                                              \
    pf0_.d[3] = hi ? q67_ : t23_;                                              \
    pf1_.d[0] = hi ? tcd_ : q89_;                                              \
    pf1_.d[1] = hi ? tef_ : qab_;                                              \
    pf1_.d[2] = hi ? qcd_ : t89_;                                              \
    pf1_.d[3] = hi ? qef_ : tab_;                                              \
    const s16x8 vf00_ = *(const s16x8*)(vr0_);                                 \
    const s16x8 vf01_ = *(const s16x8*)(vr0_ + 16);                            \
    const s16x8 vf10_ = *(const s16x8*)(vr1_);                                 \
    const s16x8 vf11_ = *(const s16x8*)(vr1_ + 16);                            \
    O[0] = __builtin_amdgcn_mfma_f32_32x32x16_bf16(vf00_, pf0_.v, O[0], 0,0,0);\
    O[0] = __builtin_amdgcn_mfma_f32_32x32x16_bf16(vf01_, pf1_.v, O[0], 0,0,0);\
    O[1] = __builtin_amdgcn_mfma_f32_32x32x16_bf16(vf10_, pf0_.v, O[1], 0,0,0);\
    O[1] = __builtin_amdgcn_mfma_f32_32x32x16_bf16(vf11_, pf1_.v, O[1], 0,0,0);\
  }

__global__ __launch_bounds__(256, 2) void attn_kernel(const unsigned short* __restrict__ q_ws,
                                                      const unsigned short* __restrict__ k_ws,
                                                      const unsigned short* __restrict__ vT,
                                                      float* __restrict__ out) {
  __shared__ float o_sm[2][4][32][68];   // [tile][wave][q][h] padded
  __shared__ float lm_sm[2][4][32][2];

  const int wv = threadIdx.x >> 6, lane = threadIdx.x & 63;
  const int qi = lane & 31, hi = lane >> 5;
  const int hi8 = 8 * hi, hi4 = 4 * hi;

  const int bid = blockIdx.x;             // 0..511
  const int b = bid & 7;                  // batch <-> XCD alignment
  const int pr = bid >> 3;                // 0..63
  const int tiA = pr, tiB = 127 - pr;     // paired long/short 32-row tiles
  const int t0A = tiA * 32, t0B = tiB * 32;

  const unsigned short* kptr = k_ws + (size_t)b * TS * HS;
  const unsigned short* vptr = vT + (size_t)b * HS * TS;
  const unsigned short* qrA = q_ws + (size_t)(b * TS + t0A + qi) * HS + hi8;
  const unsigned short* qrB = q_ws + (size_t)(b * TS + t0B + qi) * HS + hi8;

  s16x8 qfA[4], qfB[4];
#pragma unroll
  for (int kk = 0; kk < 4; ++kk) {
    qfA[kk] = *(const s16x8*)(qrA + 16 * kk);
    qfB[kk] = *(const s16x8*)(qrB + 16 * kk);
  }

  f32x16 oA[2], oB[2];
#pragma unroll
  for (int r = 0; r < 16; ++r) { oA[0][r] = 0.f; oA[1][r] = 0.f; oB[0][r] = 0.f; oB[1][r] = 0.f; }
  float mA = -1e30f, lA = 0.f, mB = -1e30f, lB = 0.f;

  const int ntA = tiA + 1, ntB = tiB + 1;
  for (int it = wv; it < ntB; it += 4) {
    const int s0 = it * 32;
    if (it < ntA) TILE32(s0, it == tiA, qfA, mA, lA, oA)
    TILE32(s0, it == tiB, qfB, mB, lB, oB)
  }

  // ---- partials to LDS ----
#pragma unroll
  for (int ht = 0; ht < 2; ++ht)
#pragma unroll
    for (int r = 0; r < 16; ++r) {
      const int h = ht * 32 + (r & 3) + 8 * (r >> 2) + hi4;
      o_sm[0][wv][qi][h] = oA[ht][r];
      o_sm[1][wv][qi][h] = oB[ht][r];
    }
  if (lane < 32) {
    lm_sm[0][wv][lane][0] = mA; lm_sm[0][wv][lane][1] = lA;
    lm_sm[1][wv][lane][0] = mB; lm_sm[1][wv][lane][1] = lB;
  }
  __syncthreads();

  // ---- merge 4 partials per tile; thread owns (q, 8 h) ----
  const int q = threadIdx.x >> 3;         // 0..31
  const int h0 = (threadIdx.x & 7) * 8;   // 0..56
  const int t0X[2] = {t0A, t0B};
#pragma unroll
  for (int X = 0; X < 2; ++X) {
    const float m0v = lm_sm[X][0][q][0], m1v = lm_sm[X][1][q][0];
    const float m2v = lm_sm[X][2][q][0], m3v = lm_sm[X][3][q][0];
    const float M = fmaxf(fmaxf(m0v, m1v), fmaxf(m2v, m3v));
    const float w0 = __builtin_amdgcn_exp2f(m0v - M);
    const float w1 = __builtin_amdgcn_exp2f(m1v - M);
    const float w2 = __builtin_amdgcn_exp2f(m2v - M);
    const float w3 = __builtin_amdgcn_exp2f(m3v - M);
    const float L = w0 * lm_sm[X][0][q][1] + w1 * lm_sm[X][1][q][1] +
                    w2 * lm_sm[X][2][q][1] + w3 * lm_sm[X][3][q][1];
    const float inv = 1.0f / L;
    float rv[8];
#pragma unroll
    for (int j = 0; j < 8; ++j)
      rv[j] = (w0 * o_sm[X][0][q][h0 + j] + w1 * o_sm[X][1][q][h0 + j] +
               w2 * o_sm[X][2][q][h0 + j] + w3 * o_sm[X][3][q][h0 + j]) * inv;
    float* ob = out + ((size_t)(b * TS + t0X[X] + q)) * HS + h0;
    *(float4*)(ob)     = float4{rv[0], rv[1], rv[2], rv[3]};
    *(float4*)(ob + 4) = float4{rv[4], rv[5], rv[6], rv[7]};
  }
}

extern "C" void kernel_launch(void* const* d_in, const int* in_sizes, int n_in,
                              void* d_out, int out_size, void* d_ws, size_t ws_size,
                              hipStream_t stream) {
  const float* x  = (const float*)d_in[0];
  const float* Wk = (const float*)d_in[1];
  const float* Wq = (const float*)d_in[2];
  const float* Wv = (const float*)d_in[3];
  float* out = (float*)d_out;

  unsigned short* wT   = (unsigned short*)d_ws;
  unsigned short* q_ws = wT + 192 * 1024;
  unsigned short* k_ws = q_ws + (size_t)NROW * HS;
  unsigned short* vT   = k_ws + (size_t)NROW * HS;

  wt_kernel<<<dim3(768), dim3(256), 0, stream>>>(Wk, Wq, Wv, wT);
  qkv_kernel<<<dim3(512), dim3(512), 0, stream>>>(x, wT, q_ws, k_ws, vT);
  attn_kernel<<<dim3(512), dim3(256), 0, stream>>>(q_ws, k_ws, vT, out);
}

// Round 12
// 122.300 us; speedup vs baseline: 1.1019x; 1.1019x over previous
//
#include <hip/hip_runtime.h>
#include <hip/hip_bf16.h>

// Head: k/q/v projection + causal softmax attention, single head.
// B=8, T=4096, C=1024, H=64. All inputs fp32; output fp32.
//   k0: wT[n][k] bf16 transpose of [Wq|Wk|Wv]  (q cols pre-scaled by 0.125*log2e)
//   k1: qkv v5: ALL VMEM via global_load_lds (x AND wT) -> compiler cannot
//       sink/reorder anything; counted vmcnt(5), double-buffered LDS, raw
//       barriers. 512 blocks x 512 thd = 8 waves (4 row-groups x 2 K-halves),
//       16 phases of K=32, LDS merge of K-halves.
//       R8/R9/R10 lesson: register prefetch gets machine-sunk (VGPR 68/52/48);
//       mixing tracked loads with manual vmcnt breaks the counting.
//   k2: flash attention (R8-verified): 32x32x16 swapped-operand, lane-local
//       softmax, shfl_xor(32) exchanges, paired (ti,127-ti) tiles, 4-way KV
//       split, LDS merge.

#define HS 64
#define NE 1024
#define NB 8
#define TS 4096
#define NROW (NB * TS)  // 32768

#define QKV_BUFSZ 40960   // per double-buffer half: 24576 W + 16384 X
#define QKV_XBASE 24576

typedef __attribute__((ext_vector_type(4)))  float f32x4;
typedef __attribute__((ext_vector_type(16))) float f32x16;
typedef __attribute__((ext_vector_type(8)))  short s16x8;   // bf16x8 MFMA fragment
typedef __attribute__((ext_vector_type(4)))  float vfloat4;

__device__ __forceinline__ unsigned short f2bf(float x) {
  return __builtin_bit_cast(unsigned short, __float2bfloat16(x));
}
__device__ __forceinline__ unsigned pkbf(float lo, float hi) {
  return (unsigned)f2bf(lo) | ((unsigned)f2bf(hi) << 16);
}

union ABFrag { s16x8 v; unsigned d[4]; };

__device__ __forceinline__ void gl_lds16(const void* g, const unsigned char* l) {
  __builtin_amdgcn_global_load_lds(
      (const __attribute__((address_space(1))) unsigned int*)(g),
      (__attribute__((address_space(3))) unsigned int*)(l), 16, 0, 0);
}

// ---------------- kernel 0: weight transpose+cast ----------------
__global__ __launch_bounds__(256) void wt_kernel(const float* __restrict__ Wk,
                                                 const float* __restrict__ Wq,
                                                 const float* __restrict__ Wv,
                                                 unsigned short* __restrict__ wT) {
  int gid = blockIdx.x * 256 + threadIdx.x;   // 0..196607
  int n = gid >> 10, k = gid & 1023;
  const float* W = (n < 64) ? Wq : (n < 128) ? Wk : Wv;
  float s = (n < 64) ? 0.18033688011112042f : 1.0f;  // 0.125 * log2(e)
  wT[gid] = f2bf(W[k * 64 + (n & 63)] * s);
}

// ---------------- kernel 1: fused QKV projection v5 ----------------
// Block 512 thd = 8 waves: wave w -> rg=w>>1 (16-row group), kh=w&1 (K half).
// Per phase (K=32 per kh): stage W (2 kh x 12288B: slot sk=192g+n, 16B of
// wT[n][kh*512+c*32+8g..]) and X (2 kh x 8192B: slot s=g'*128+row*2+half,
// 16B of x[m0+row][kh*512+c*32+8g'+4half..]) via global_load_lds only.
// gl_lds dest = wave-uniform base + lane*16 (HW rule); slot->lane mappings
// verified not to cross region boundaries mid-wave.
// Reads: A = 2x b128 fp32 (4-way bank conflict, 1.58x, OK); B = 12x b128
// (2-way, free). Phase: vmcnt(5) -> barrier -> MFMA -> barrier -> issue c+2.
__global__ __launch_bounds__(512, 4) void qkv_kernel(const float* __restrict__ x,
                                                     const unsigned short* __restrict__ wT,
                                                     unsigned short* __restrict__ q_ws,
                                                     unsigned short* __restrict__ k_ws,
                                                     unsigned short* __restrict__ vT) {
  __shared__ __align__(16) unsigned char smem[2 * QKV_BUFSZ];  // 81920 B
  const int t = threadIdx.x;
  const int w = t >> 6, lane = t & 63;
  const int rg = w >> 1, kh = w & 1;
  const int g = lane >> 4, nn = lane & 15;
  const int m0blk = blockIdx.x * 64;
  const int m0 = m0blk + rg * 16;

  f32x4 acc[12];
#pragma unroll
  for (int i = 0; i < 12; ++i) acc[i] = f32x4{0.f, 0.f, 0.f, 0.f};

  // ---- staging source pointers (per thread) ----
  // X: instr j in {0,1} covers kh=j. s' = w*64+lane: g'=w>>1, row=(s'>>1)&63,
  // half=lane&1. src = x[m0blk+row][j*512 + c*32 + 8g' + 4half]
  const int srow = ((w * 64 + lane) >> 1) & 63;
  const int sg = w >> 1, shalf = lane & 1;
  const float* xsrc0 = x + (size_t)(m0blk + srow) * NE + 0 * 512 + sg * 8 + shalf * 4;
  const float* xsrc1 = x + (size_t)(m0blk + srow) * NE + 1 * 512 + sg * 8 + shalf * 4;
  const int xd0 = QKV_XBASE + 0 * 8192 + w * 1024;   // uniform per wave
  const int xd1 = QKV_XBASE + 1 * 8192 + w * 1024;

  // W: instr j2 in {0,1,2}: ws = j2*512 + w*64 + lane; kh_s = ws/768,
  // sk = ws%768 = g2*192 + n2. src = wT[n2][kh_s*512 + c*32 + 8g2]
  int wd[3];
  const unsigned short* wsrc[3];
#pragma unroll
  for (int j2 = 0; j2 < 3; ++j2) {
    const int ws = j2 * 512 + w * 64 + lane;
    const int kh_s = ws / 768, sk = ws % 768;
    const int g2 = sk / 192, n2 = sk % 192;
    wsrc[j2] = wT + (size_t)n2 * NE + kh_s * 512 + g2 * 8;
    wd[j2] = kh_s * 12288 + ((j2 * 512 + w * 64) % 768) * 16;  // uniform per wave
  }

  // ---- read offsets (per thread) ----
  const int abase = QKV_XBASE + kh * 8192 + g * 2048 + (16 * rg + nn) * 32;
  const int wbase = kh * 12288 + (g * 192 + nn) * 16;

  // ---- prologue: clusters for chunk 0 -> buf0, chunk 1 -> buf1 ----
  {
    unsigned char* b0 = smem;
    gl_lds16(xsrc0, b0 + xd0);
    gl_lds16(xsrc1, b0 + xd1);
    gl_lds16(wsrc[0], b0 + wd[0]);
    gl_lds16(wsrc[1], b0 + wd[1]);
    gl_lds16(wsrc[2], b0 + wd[2]);
    __builtin_amdgcn_sched_barrier(0);
    unsigned char* b1 = smem + QKV_BUFSZ;
    gl_lds16(xsrc0 + 32, b1 + xd0);
    gl_lds16(xsrc1 + 32, b1 + xd1);
    gl_lds16(wsrc[0] + 32, b1 + wd[0]);
    gl_lds16(wsrc[1] + 32, b1 + wd[1]);
    gl_lds16(wsrc[2] + 32, b1 + wd[2]);
    __builtin_amdgcn_sched_barrier(0);
  }

#define PHASE(C, VM, DOISS)                                                    \
  {                                                                            \
    asm volatile("s_waitcnt vmcnt(" #VM ")" ::: "memory");                     \
    __builtin_amdgcn_s_barrier();                                              \
    __builtin_amdgcn_sched_barrier(0);                                         \
    const unsigned char* bb_ = smem + ((C) & 1) * QKV_BUFSZ;                   \
    const vfloat4 a0_ = *(const vfloat4*)(bb_ + abase);                        \
    const vfloat4 a1_ = *(const vfloat4*)(bb_ + abase + 16);                   \
    ABFrag af;                                                                 \
    af.d[0] = pkbf(a0_.x, a0_.y); af.d[1] = pkbf(a0_.z, a0_.w);                \
    af.d[2] = pkbf(a1_.x, a1_.y); af.d[3] = pkbf(a1_.z, a1_.w);                \
    _Pragma("unroll")                                                          \
    for (int i = 0; i < 12; ++i) {                                             \
      const s16x8 bf = *(const s16x8*)(bb_ + wbase + i * 256);                 \
      acc[i] = __builtin_amdgcn_mfma_f32_16x16x32_bf16(af.v, bf, acc[i], 0, 0, 0); \
    }                                                                          \
    __builtin_amdgcn_sched_barrier(0);                                         \
    __builtin_amdgcn_s_barrier();                                              \
    __builtin_amdgcn_sched_barrier(0);                                         \
    if (DOISS) {                                                               \
      unsigned char* db_ = smem + ((C) & 1) * QKV_BUFSZ;                       \
      const int cc_ = ((C) + 2) * 32;                                          \
      gl_lds16(xsrc0 + cc_, db_ + xd0);                                        \
      gl_lds16(xsrc1 + cc_, db_ + xd1);                                        \
      gl_lds16(wsrc[0] + cc_, db_ + wd[0]);                                    \
      gl_lds16(wsrc[1] + cc_, db_ + wd[1]);                                    \
      gl_lds16(wsrc[2] + cc_, db_ + wd[2]);                                    \
    }                                                                          \
    __builtin_amdgcn_sched_barrier(0);                                         \
  }

#pragma unroll
  for (int c = 0; c < 14; ++c) PHASE(c, 5, 1)
  PHASE(14, 5, 0)
  PHASE(15, 0, 0)
#undef PHASE

  // ---- merge K halves (kh=1 -> LDS, kh=0 adds + stores) ----
  __syncthreads();
  float* msm = (float*)smem;
  const int mofs = (rg * 64 + lane) * 48;
  if (kh == 1) {
#pragma unroll
    for (int i = 0; i < 12; ++i) *(f32x4*)&msm[mofs + i * 4] = acc[i];
  }
  __syncthreads();
  if (kh == 0) {
#pragma unroll
    for (int i = 0; i < 12; ++i) acc[i] += *(const f32x4*)&msm[mofs + i * 4];
    const int rbase = m0 + 4 * g;
#pragma unroll
    for (int i = 0; i < 12; ++i) {
      const int c = 16 * i + nn;
#pragma unroll
      for (int j = 0; j < 4; ++j) {
        const int rr = rbase + j;
        const unsigned short h = f2bf(acc[i][j]);
        if (c < 64) {
          q_ws[(size_t)rr * HS + c] = h;
        } else if (c < 128) {
          k_ws[(size_t)rr * HS + (c - 64)] = h;
        } else {
          const int b = rr >> 12, tt = rr & 4095;
          vT[((size_t)(b * HS + (c - 128))) * TS + tt] = h;
        }
      }
    }
  }
}

// ---------------- kernel 2: causal flash attention, 32x32 lane-local -------
// S^T(32kv x 32q) = sum_kk mfma32x32x16(K-frag, Q^T-frag). Lane (qi,hi) holds
// st_[r] = S^T[kv=(r&3)+8*(r>>2)+4hi][q=qi]; the other 16 kv live in lane^32.
// Reduces and P^T B-frag assembly use __shfl_xor(...,32).
#define TILE32(S0, DIAG, QF, M_RUN, L_RUN, O)                                  \
  {                                                                            \
    const int s0_ = (S0);                                                      \
    const unsigned short* kr_ = kptr + (size_t)(s0_ + qi) * HS + hi8;          \
    const s16x8 ka0_ = *(const s16x8*)(kr_);                                   \
    const s16x8 ka1_ = *(const s16x8*)(kr_ + 16);                              \
    const s16x8 ka2_ = *(const s16x8*)(kr_ + 32);                              \
    const s16x8 ka3_ = *(const s16x8*)(kr_ + 48);                              \
    const unsigned short* vr0_ = vptr + (size_t)qi * TS + s0_ + hi8;           \
    const unsigned short* vr1_ = vptr + (size_t)(32 + qi) * TS + s0_ + hi8;    \
    f32x16 st_;                                                                \
    _Pragma("unroll") for (int r = 0; r < 16; ++r) st_[r] = 0.f;               \
    st_ = __builtin_amdgcn_mfma_f32_32x32x16_bf16(ka0_, QF[0], st_, 0, 0, 0);  \
    st_ = __builtin_amdgcn_mfma_f32_32x32x16_bf16(ka1_, QF[1], st_, 0, 0, 0);  \
    st_ = __builtin_amdgcn_mfma_f32_32x32x16_bf16(ka2_, QF[2], st_, 0, 0, 0);  \
    st_ = __builtin_amdgcn_mfma_f32_32x32x16_bf16(ka3_, QF[3], st_, 0, 0, 0);  \
    if (DIAG) {                                                                \
      _Pragma("unroll") for (int r = 0; r < 16; ++r) {                         \
        const int kvl_ = (r & 3) + 8 * (r >> 2) + hi4;                         \
        if (kvl_ > qi) st_[r] = -1e30f;                                        \
      }                                                                        \
    }                                                                          \
    float mx_ =                                                                \
      fmaxf(fmaxf(fmaxf(fmaxf(st_[0], st_[1]), fmaxf(st_[2], st_[3])),         \
                  fmaxf(fmaxf(st_[4], st_[5]), fmaxf(st_[6], st_[7]))),        \
            fmaxf(fmaxf(fmaxf(st_[8], st_[9]), fmaxf(st_[10], st_[11])),       \
                  fmaxf(fmaxf(st_[12], st_[13]), fmaxf(st_[14], st_[15]))));   \
    mx_ = fmaxf(mx_, __shfl_xor(mx_, 32, 64));                                 \
    const float mn_ = fmaxf(M_RUN, mx_);                                       \
    if (__ballot(mn_ > M_RUN)) {                                               \
      const float fs_ = __builtin_amdgcn_exp2f(M_RUN - mn_);                   \
      _Pragma("unroll") for (int r = 0; r < 16; ++r) {                         \
        O[0][r] *= fs_; O[1][r] *= fs_;                                        \
      }                                                                        \
      L_RUN *= fs_;                                                            \
      M_RUN = mn_;                                                             \
    }                                                                          \
    float p_[16];                                                              \
    _Pragma("unroll") for (int r = 0; r < 16; ++r)                             \
      p_[r] = __builtin_amdgcn_exp2f(st_[r] - M_RUN);                          \
    float sm_ = ((p_[0] + p_[1]) + (p_[2] + p_[3])) +                          \
                ((p_[4] + p_[5]) + (p_[6] + p_[7]));                           \
    sm_ += ((p_[8] + p_[9]) + (p_[10] + p_[11])) +                             \
           ((p_[12] + p_[13]) + (p_[14] + p_[15]));                            \
    sm_ += __shfl_xor(sm_, 32, 64);                                            \
    L_RUN += sm_;                                                              \
    const unsigned q01_ = pkbf(p_[0], p_[1]),   q23_ = pkbf(p_[2], p_[3]);     \
    const unsigned q45_ = pkbf(p_[4], p_[5]),   q67_ = pkbf(p_[6], p_[7]);     \
    const unsigned q89_ = pkbf(p_[8], p_[9]),   qab_ = pkbf(p_[10], p_[11]);   \
    const unsigned qcd_ = pkbf(p_[12], p_[13]), qef_ = pkbf(p_[14], p_[15]);   \
    const unsigned t01_ = (unsigned)__shfl_xor((int)q01_, 32, 64);             \
    const unsigned t23_ = (unsigned)__shfl_xor((int)q23_, 32, 64);             \
    const unsigned t45_ = (unsigned)__shfl_xor((int)q45_, 32, 64);             \
    const unsigned t67_ = (unsigned)__shfl_xor((int)q67_, 32, 64);             \
    const unsigned t89_ = (unsigned)__shfl_xor((int)q89_, 32, 64);             \
    const unsigned tab_ = (unsigned)__shfl_xor((int)qab_, 32, 64);             \
    const unsigned tcd_ = (unsigned)__shfl_xor((int)qcd_, 32, 64);             \
    const unsigned tef_ = (unsigned)__shfl_xor((int)qef_, 32, 64);             \
    ABFrag pf0_, pf1_;                                                         \
    pf0_.d[0] = hi ? t45_ : q01_;                                              \
    pf0_.d[1] = hi ? t67_ : q23_;                                              \
    pf0_.d[2] = hi ? q45_ : t01_;                                              \
    pf0_.d[3] = hi ? q67_ : t23_;                                              \
    pf1_.d[0] = hi ? tcd_ : q89_;                                              \
    pf1_.d[1] = hi ? tef_ : qab_;                                              \
    pf1_.d[2] = hi ? qcd_ : t89_;                                              \
    pf1_.d[3] = hi ? qef_ : tab_;                                              \
    const s16x8 vf00_ = *(const s16x8*)(vr0_);                                 \
    const s16x8 vf01_ = *(const s16x8*)(vr0_ + 16);                            \
    const s16x8 vf10_ = *(const s16x8*)(vr1_);                                 \
    const s16x8 vf11_ = *(const s16x8*)(vr1_ + 16);                            \
    O[0] = __builtin_amdgcn_mfma_f32_32x32x16_bf16(vf00_, pf0_.v, O[0], 0,0,0);\
    O[0] = __builtin_amdgcn_mfma_f32_32x32x16_bf16(vf01_, pf1_.v, O[0], 0,0,0);\
    O[1] = __builtin_amdgcn_mfma_f32_32x32x16_bf16(vf10_, pf0_.v, O[1], 0,0,0);\
    O[1] = __builtin_amdgcn_mfma_f32_32x32x16_bf16(vf11_, pf1_.v, O[1], 0,0,0);\
  }

__global__ __launch_bounds__(256, 2) void attn_kernel(const unsigned short* __restrict__ q_ws,
                                                      const unsigned short* __restrict__ k_ws,
                                                      const unsigned short* __restrict__ vT,
                                                      float* __restrict__ out) {
  __shared__ float o_sm[2][4][32][68];   // [tile][wave][q][h] padded
  __shared__ float lm_sm[2][4][32][2];

  const int wv = threadIdx.x >> 6, lane = threadIdx.x & 63;
  const int qi = lane & 31, hi = lane >> 5;
  const int hi8 = 8 * hi, hi4 = 4 * hi;

  const int bid = blockIdx.x;             // 0..511
  const int b = bid & 7;                  // batch <-> XCD alignment
  const int pr = bid >> 3;                // 0..63
  const int tiA = pr, tiB = 127 - pr;     // paired long/short 32-row tiles
  const int t0A = tiA * 32, t0B = tiB * 32;

  const unsigned short* kptr = k_ws + (size_t)b * TS * HS;
  const unsigned short* vptr = vT + (size_t)b * HS * TS;
  const unsigned short* qrA = q_ws + (size_t)(b * TS + t0A + qi) * HS + hi8;
  const unsigned short* qrB = q_ws + (size_t)(b * TS + t0B + qi) * HS + hi8;

  s16x8 qfA[4], qfB[4];
#pragma unroll
  for (int kk = 0; kk < 4; ++kk) {
    qfA[kk] = *(const s16x8*)(qrA + 16 * kk);
    qfB[kk] = *(const s16x8*)(qrB + 16 * kk);
  }

  f32x16 oA[2], oB[2];
#pragma unroll
  for (int r = 0; r < 16; ++r) { oA[0][r] = 0.f; oA[1][r] = 0.f; oB[0][r] = 0.f; oB[1][r] = 0.f; }
  float mA = -1e30f, lA = 0.f, mB = -1e30f, lB = 0.f;

  const int ntA = tiA + 1, ntB = tiB + 1;
  for (int it = wv; it < ntB; it += 4) {
    const int s0 = it * 32;
    if (it < ntA) TILE32(s0, it == tiA, qfA, mA, lA, oA)
    TILE32(s0, it == tiB, qfB, mB, lB, oB)
  }

  // ---- partials to LDS ----
#pragma unroll
  for (int ht = 0; ht < 2; ++ht)
#pragma unroll
    for (int r = 0; r < 16; ++r) {
      const int h = ht * 32 + (r & 3) + 8 * (r >> 2) + hi4;
      o_sm[0][wv][qi][h] = oA[ht][r];
      o_sm[1][wv][qi][h] = oB[ht][r];
    }
  if (lane < 32) {
    lm_sm[0][wv][lane][0] = mA; lm_sm[0][wv][lane][1] = lA;
    lm_sm[1][wv][lane][0] = mB; lm_sm[1][wv][lane][1] = lB;
  }
  __syncthreads();

  // ---- merge 4 partials per tile; thread owns (q, 8 h) ----
  const int q = threadIdx.x >> 3;         // 0..31
  const int h0 = (threadIdx.x & 7) * 8;   // 0..56
  const int t0X[2] = {t0A, t0B};
#pragma unroll
  for (int X = 0; X < 2; ++X) {
    const float m0v = lm_sm[X][0][q][0], m1v = lm_sm[X][1][q][0];
    const float m2v = lm_sm[X][2][q][0], m3v = lm_sm[X][3][q][0];
    const float M = fmaxf(fmaxf(m0v, m1v), fmaxf(m2v, m3v));
    const float w0 = __builtin_amdgcn_exp2f(m0v - M);
    const float w1 = __builtin_amdgcn_exp2f(m1v - M);
    const float w2 = __builtin_amdgcn_exp2f(m2v - M);
    const float w3 = __builtin_amdgcn_exp2f(m3v - M);
    const float L = w0 * lm_sm[X][0][q][1] + w1 * lm_sm[X][1][q][1] +
                    w2 * lm_sm[X][2][q][1] + w3 * lm_sm[X][3][q][1];
    const float inv = 1.0f / L;
    float rv[8];
#pragma unroll
    for (int j = 0; j < 8; ++j)
      rv[j] = (w0 * o_sm[X][0][q][h0 + j] + w1 * o_sm[X][1][q][h0 + j] +
               w2 * o_sm[X][2][q][h0 + j] + w3 * o_sm[X][3][q][h0 + j]) * inv;
    float* ob = out + ((size_t)(b * TS + t0X[X] + q)) * HS + h0;
    *(float4*)(ob)     = float4{rv[0], rv[1], rv[2], rv[3]};
    *(float4*)(ob + 4) = float4{rv[4], rv[5], rv[6], rv[7]};
  }
}

extern "C" void kernel_launch(void* const* d_in, const int* in_sizes, int n_in,
                              void* d_out, int out_size, void* d_ws, size_t ws_size,
                              hipStream_t stream) {
  const float* x  = (const float*)d_in[0];
  const float* Wk = (const float*)d_in[1];
  const float* Wq = (const float*)d_in[2];
  const float* Wv = (const float*)d_in[3];
  float* out = (float*)d_out;

  unsigned short* wT   = (unsigned short*)d_ws;
  unsigned short* q_ws = wT + 192 * 1024;
  unsigned short* k_ws = q_ws + (size_t)NROW * HS;
  unsigned short* vT   = k_ws + (size_t)NROW * HS;

  wt_kernel<<<dim3(768), dim3(256), 0, stream>>>(Wk, Wq, Wv, wT);
  qkv_kernel<<<dim3(512), dim3(512), 0, stream>>>(x, wT, q_ws, k_ws, vT);
  attn_kernel<<<dim3(512), dim3(256), 0, stream>>>(q_ws, k_ws, vT, out);
}

// Round 15
// 100.435 us; speedup vs baseline: 1.3418x; 1.2177x over previous
//
#include <hip/hip_runtime.h>
#include <hip/hip_bf16.h>

// Head: k/q/v projection + causal softmax attention, single head.
// B=8, T=4096, C=1024, H=64. All inputs fp32; output fp32.
//   k0: wT2 = [Wq|Wk|Wv]^T in STAGED-CHUNK layout: for (kh,cc) a contiguous
//       12KB image of 768 slots x 16B, slot sk=g*192+n = wT[n][kh*512+cc*32+8g..+7]
//       (q cols pre-scaled by 0.125*log2e). Staging reads become contiguous.
//   k1: qkv v6: all VMEM via global_load_lds; W-stage = 3x contiguous-1KB
//       reads/wave, x-stage = row-major [64][128B] (8-lane/128B segments).
//       v5's scattered staging (64 transactions/instr) was the suspect for
//       the 72us-vs-22us-floor gap. vmcnt(5), double buffer, raw barriers.
//   k2: flash attention (R8-verified): 32x32x16 swapped-operand, lane-local
//       softmax, shfl_xor(32) exchanges, paired (ti,127-ti) tiles, 4-way KV
//       split, LDS merge.

#define HS 64
#define NE 1024
#define NB 8
#define TS 4096
#define NROW (NB * TS)  // 32768

#define QKV_BUFSZ 40960   // per double-buffer half: 24576 W + 16384 X
#define QKV_XBASE 24576

typedef __attribute__((ext_vector_type(4)))  float f32x4;
typedef __attribute__((ext_vector_type(16))) float f32x16;
typedef __attribute__((ext_vector_type(8)))  short s16x8;   // bf16x8 MFMA fragment
typedef __attribute__((ext_vector_type(4)))  float vfloat4;

__device__ __forceinline__ unsigned short f2bf(float x) {
  return __builtin_bit_cast(unsigned short, __float2bfloat16(x));
}
__device__ __forceinline__ unsigned pkbf(float lo, float hi) {
  return (unsigned)f2bf(lo) | ((unsigned)f2bf(hi) << 16);
}

union ABFrag { s16x8 v; unsigned d[4]; };

__device__ __forceinline__ void gl_lds16(const void* g, const unsigned char* l) {
  __builtin_amdgcn_global_load_lds(
      (const __attribute__((address_space(1))) unsigned int*)(g),
      (__attribute__((address_space(3))) unsigned int*)(l), 16, 0, 0);
}

// ---------------- kernel 0: weight transpose+cast, staged-chunk layout ----
__global__ __launch_bounds__(256) void wt_kernel(const float* __restrict__ Wk,
                                                 const float* __restrict__ Wq,
                                                 const float* __restrict__ Wv,
                                                 unsigned short* __restrict__ wT2) {
  int gid = blockIdx.x * 256 + threadIdx.x;   // 0..196607
  int j = gid & 7;
  int t1 = gid >> 3;          // 0..24575
  int sk = t1 % 768;
  int ch = t1 / 768;          // 0..31 = kh*16 + cc
  int kh = ch >> 4, cc = ch & 15;
  int g = sk / 192, n = sk % 192;
  int k = kh * 512 + cc * 32 + g * 8 + j;
  const float* W = (n < 64) ? Wq : (n < 128) ? Wk : Wv;
  float s = (n < 64) ? 0.18033688011112042f : 1.0f;  // 0.125 * log2(e)
  wT2[gid] = f2bf(W[k * 64 + (n & 63)] * s);
}

// ---------------- kernel 1: fused QKV projection v6 ----------------
// Block 512 thd = 8 waves: wave w -> rg=w>>1 (16-row group), kh=w&1 (K half).
// Per phase c (K=32 per kh):
//   W: wave stages slots rg*192..+191 of (kh,c): 3 gl_lds of contiguous 1KB
//      from wT2 + (kh*16+c)*6144 (ushorts).
//   X: wave stages rows rg*16..+15 (its own rows), row-major [row][128B]:
//      2 gl_lds; lane l -> row rg*16+q*8+(l>>3), 16B sub l&7; 8-lane/128B
//      coalesced segments.
// Reads: A = 2x b128 at XBASE+kh*8192+row*128+g*32 (throughput-floor bound);
//        B = 12x b128 at kh*12288+(g*192+16i+nn)*16 (v5 pattern, conflict-OK).
// Phase: vmcnt(5) -> barrier -> MFMA -> barrier -> issue cluster c+2.
__global__ __launch_bounds__(512, 4) void qkv_kernel(const float* __restrict__ x,
                                                     const unsigned short* __restrict__ wT2,
                                                     unsigned short* __restrict__ q_ws,
                                                     unsigned short* __restrict__ k_ws,
                                                     unsigned short* __restrict__ vT) {
  __shared__ __align__(16) unsigned char smem[2 * QKV_BUFSZ];  // 81920 B
  const int t = threadIdx.x;
  const int w = t >> 6, lane = t & 63;
  const int rg = w >> 1, kh = w & 1;
  const int g = lane >> 4, nn = lane & 15;
  const int m0blk = blockIdx.x * 64;
  const int m0 = m0blk + rg * 16;

  f32x4 acc[12];
#pragma unroll
  for (int i = 0; i < 12; ++i) acc[i] = f32x4{0.f, 0.f, 0.f, 0.f};

  // ---- staging sources ----
  // W: per-thread base; phase adds c*6144 ushorts; instr p adds p*512.
  const unsigned short* wsrcA = wT2 + (size_t)kh * 98304 + (size_t)(rg * 192 + lane) * 8;
  const int wd0 = kh * 12288 + rg * 3072;   // wave-uniform dest; +p*1024
  // X: instr q in {0,1}: row = rg*16 + q*8 + (lane>>3), sub = lane&7.
  const float* xsrc0 = x + (size_t)(m0blk + rg * 16 + 0 + (lane >> 3)) * NE + kh * 512 + (lane & 7) * 4;
  const float* xsrc1 = x + (size_t)(m0blk + rg * 16 + 8 + (lane >> 3)) * NE + kh * 512 + (lane & 7) * 4;
  const int xd0 = QKV_XBASE + kh * 8192 + rg * 2048;        // wave-uniform
  const int xd1 = xd0 + 1024;

  // ---- read offsets ----
  const int abase = QKV_XBASE + kh * 8192 + (rg * 16 + nn) * 128 + g * 32;
  const int wbase = kh * 12288 + (g * 192 + nn) * 16;

  // ---- prologue: cluster(chunk0)->buf0, cluster(chunk1)->buf1 ----
  {
    unsigned char* b0 = smem;
    gl_lds16(wsrcA, b0 + wd0);
    gl_lds16(wsrcA + 512, b0 + wd0 + 1024);
    gl_lds16(wsrcA + 1024, b0 + wd0 + 2048);
    gl_lds16(xsrc0, b0 + xd0);
    gl_lds16(xsrc1, b0 + xd1);
    __builtin_amdgcn_sched_barrier(0);
    unsigned char* b1 = smem + QKV_BUFSZ;
    gl_lds16(wsrcA + 6144, b1 + wd0);
    gl_lds16(wsrcA + 6144 + 512, b1 + wd0 + 1024);
    gl_lds16(wsrcA + 6144 + 1024, b1 + wd0 + 2048);
    gl_lds16(xsrc0 + 32, b1 + xd0);
    gl_lds16(xsrc1 + 32, b1 + xd1);
    __builtin_amdgcn_sched_barrier(0);
  }

#define PHASE(C, VM, DOISS)                                                    \
  {                                                                            \
    asm volatile("s_waitcnt vmcnt(" #VM ")" ::: "memory");                     \
    __builtin_amdgcn_s_barrier();                                              \
    __builtin_amdgcn_sched_barrier(0);                                         \
    const unsigned char* bb_ = smem + ((C) & 1) * QKV_BUFSZ;                   \
    const vfloat4 a0_ = *(const vfloat4*)(bb_ + abase);                        \
    const vfloat4 a1_ = *(const vfloat4*)(bb_ + abase + 16);                   \
    ABFrag af;                                                                 \
    af.d[0] = pkbf(a0_.x, a0_.y); af.d[1] = pkbf(a0_.z, a0_.w);                \
    af.d[2] = pkbf(a1_.x, a1_.y); af.d[3] = pkbf(a1_.z, a1_.w);                \
    _Pragma("unroll")                                                          \
    for (int i = 0; i < 12; ++i) {                                             \
      const s16x8 bf = *(const s16x8*)(bb_ + wbase + i * 256);                 \
      acc[i] = __builtin_amdgcn_mfma_f32_16x16x32_bf16(af.v, bf, acc[i], 0, 0, 0); \
    }                                                                          \
    __builtin_amdgcn_sched_barrier(0);                                         \
    __builtin_amdgcn_s_barrier();                                              \
    __builtin_amdgcn_sched_barrier(0);                                         \
    if (DOISS) {                                                               \
      unsigned char* db_ = smem + ((C) & 1) * QKV_BUFSZ;                       \
      const int wof_ = ((C) + 2) * 6144;                                       \
      const int xof_ = ((C) + 2) * 32;                                         \
      gl_lds16(wsrcA + wof_, db_ + wd0);                                       \
      gl_lds16(wsrcA + wof_ + 512, db_ + wd0 + 1024);                          \
      gl_lds16(wsrcA + wof_ + 1024, db_ + wd0 + 2048);                         \
      gl_lds16(xsrc0 + xof_, db_ + xd0);                                       \
      gl_lds16(xsrc1 + xof_, db_ + xd1);                                       \
    }                                                                          \
    __builtin_amdgcn_sched_barrier(0);                                         \
  }

#pragma unroll
  for (int c = 0; c < 14; ++c) PHASE(c, 5, 1)
  PHASE(14, 5, 0)
  PHASE(15, 0, 0)
#undef PHASE

  // ---- merge K halves (kh=1 -> LDS, kh=0 adds + stores) ----
  __syncthreads();
  float* msm = (float*)smem;
  const int mofs = (rg * 64 + lane) * 48;
  if (kh == 1) {
#pragma unroll
    for (int i = 0; i < 12; ++i) *(f32x4*)&msm[mofs + i * 4] = acc[i];
  }
  __syncthreads();
  if (kh == 0) {
#pragma unroll
    for (int i = 0; i < 12; ++i) acc[i] += *(const f32x4*)&msm[mofs + i * 4];
    const int rbase = m0 + 4 * g;
#pragma unroll
    for (int i = 0; i < 12; ++i) {
      const int c = 16 * i + nn;
#pragma unroll
      for (int j = 0; j < 4; ++j) {
        const int rr = rbase + j;
        const unsigned short h = f2bf(acc[i][j]);
        if (c < 64) {
          q_ws[(size_t)rr * HS + c] = h;
        } else if (c < 128) {
          k_ws[(size_t)rr * HS + (c - 64)] = h;
        } else {
          const int b = rr >> 12, tt = rr & 4095;
          vT[((size_t)(b * HS + (c - 128))) * TS + tt] = h;
        }
      }
    }
  }
}

// ---------------- kernel 2: causal flash attention, 32x32 lane-local -------
// S^T(32kv x 32q) = sum_kk mfma32x32x16(K-frag, Q^T-frag). Lane (qi,hi) holds
// st_[r] = S^T[kv=(r&3)+8*(r>>2)+4hi][q=qi]; the other 16 kv live in lane^32.
// Reduces and P^T B-frag assembly use __shfl_xor(...,32).
#define TILE32(S0, DIAG, QF, M_RUN, L_RUN, O)                                  \
  {                                                                            \
    const int s0_ = (S0);                                                      \
    const unsigned short* kr_ = kptr + (size_t)(s0_ + qi) * HS + hi8;          \
    const s16x8 ka0_ = *(const s16x8*)(kr_);                                   \
    const s16x8 ka1_ = *(const s16x8*)(kr_ + 16);                              \
    const s16x8 ka2_ = *(const s16x8*)(kr_ + 32);                              \
    const s16x8 ka3_ = *(const s16x8*)(kr_ + 48);                              \
    const unsigned short* vr0_ = vptr + (size_t)qi * TS + s0_ + hi8;           \
    const unsigned short* vr1_ = vptr + (size_t)(32 + qi) * TS + s0_ + hi8;    \
    f32x16 st_;                                                                \
    _Pragma("unroll") for (int r = 0; r < 16; ++r) st_[r] = 0.f;               \
    st_ = __builtin_amdgcn_mfma_f32_32x32x16_bf16(ka0_, QF[0], st_, 0, 0, 0);  \
    st_ = __builtin_amdgcn_mfma_f32_32x32x16_bf16(ka1_, QF[1], st_, 0, 0, 0);  \
    st_ = __builtin_amdgcn_mfma_f32_32x32x16_bf16(ka2_, QF[2], st_, 0, 0, 0);  \
    st_ = __builtin_amdgcn_mfma_f32_32x32x16_bf16(ka3_, QF[3], st_, 0, 0, 0);  \
    if (DIAG) {                                                                \
      _Pragma("unroll") for (int r = 0; r < 16; ++r) {                         \
        const int kvl_ = (r & 3) + 8 * (r >> 2) + hi4;                         \
        if (kvl_ > qi) st_[r] = -1e30f;                                        \
      }                                                                        \
    }                                                                          \
    float mx_ =                                                                \
      fmaxf(fmaxf(fmaxf(fmaxf(st_[0], st_[1]), fmaxf(st_[2], st_[3])),         \
                  fmaxf(fmaxf(st_[4], st_[5]), fmaxf(st_[6], st_[7]))),        \
            fmaxf(fmaxf(fmaxf(st_[8], st_[9]), fmaxf(st_[10], st_[11])),       \
                  fmaxf(fmaxf(st_[12], st_[13]), fmaxf(st_[14], st_[15]))));   \
    mx_ = fmaxf(mx_, __shfl_xor(mx_, 32, 64));                                 \
    const float mn_ = fmaxf(M_RUN, mx_);                                       \
    if (__ballot(mn_ > M_RUN)) {                                               \
      const float fs_ = __builtin_amdgcn_exp2f(M_RUN - mn_);                   \
      _Pragma("unroll") for (int r = 0; r < 16; ++r) {                         \
        O[0][r] *= fs_; O[1][r] *= fs_;                                        \
      }                                                                        \
      L_RUN *= fs_;                                                            \
      M_RUN = mn_;                                                             \
    }                                                                          \
    float p_[16];                                                              \
    _Pragma("unroll") for (int r = 0; r < 16; ++r)                             \
      p_[r] = __builtin_amdgcn_exp2f(st_[r] - M_RUN);                          \
    float sm_ = ((p_[0] + p_[1]) + (p_[2] + p_[3])) +                          \
                ((p_[4] + p_[5]) + (p_[6] + p_[7]));                           \
    sm_ += ((p_[8] + p_[9]) + (p_[10] + p_[11])) +                             \
           ((p_[12] + p_[13]) + (p_[14] + p_[15]));                            \
    sm_ += __shfl_xor(sm_, 32, 64);                                            \
    L_RUN += sm_;                                                              \
    const unsigned q01_ = pkbf(p_[0], p_[1]),   q23_ = pkbf(p_[2], p_[3]);     \
    const unsigned q45_ = pkbf(p_[4], p_[5]),   q67_ = pkbf(p_[6], p_[7]);     \
    const unsigned q89_ = pkbf(p_[8], p_[9]),   qab_ = pkbf(p_[10], p_[11]);   \
    const unsigned qcd_ = pkbf(p_[12], p_[13]), qef_ = pkbf(p_[14], p_[15]);   \
    const unsigned t01_ = (unsigned)__shfl_xor((int)q01_, 32, 64);             \
    const unsigned t23_ = (unsigned)__shfl_xor((int)q23_, 32, 64);             \
    const unsigned t45_ = (unsigned)__shfl_xor((int)q45_, 32, 64);             \
    const unsigned t67_ = (unsigned)__shfl_xor((int)q67_, 32, 64);             \
    const unsigned t89_ = (unsigned)__shfl_xor((int)q89_, 32, 64);             \
    const unsigned tab_ = (unsigned)__shfl_xor((int)qab_, 32, 64);             \
    const unsigned tcd_ = (unsigned)__shfl_xor((int)qcd_, 32, 64);             \
    const unsigned tef_ = (unsigned)__shfl_xor((int)qef_, 32, 64);             \
    ABFrag pf0_, pf1_;                                                         \
    pf0_.d[0] = hi ? t45_ : q01_;                                              \
    pf0_.d[1] = hi ? t67_ : q23_;                                              \
    pf0_.d[2] = hi ? q45_ : t01_;                                              \
    pf0_.d[3] = hi ? q67_ : t23_;                                              \
    pf1_.d[0] = hi ? tcd_ : q89_;                                              \
    pf1_.d[1] = hi ? tef_ : qab_;                                              \
    pf1_.d[2] = hi ? qcd_ : t89_;                                              \
    pf1_.d[3] = hi ? qef_ : tab_;                                              \
    const s16x8 vf00_ = *(const s16x8*)(vr0_);                                 \
    const s16x8 vf01_ = *(const s16x8*)(vr0_ + 16);                            \
    const s16x8 vf10_ = *(const s16x8*)(vr1_);                                 \
    const s16x8 vf11_ = *(const s16x8*)(vr1_ + 16);                            \
    O[0] = __builtin_amdgcn_mfma_f32_32x32x16_bf16(vf00_, pf0_.v, O[0], 0,0,0);\
    O[0] = __builtin_amdgcn_mfma_f32_32x32x16_bf16(vf01_, pf1_.v, O[0], 0,0,0);\
    O[1] = __builtin_amdgcn_mfma_f32_32x32x16_bf16(vf10_, pf0_.v, O[1], 0,0,0);\
    O[1] = __builtin_amdgcn_mfma_f32_32x32x16_bf16(vf11_, pf1_.v, O[1], 0,0,0);\
  }

__global__ __launch_bounds__(256, 2) void attn_kernel(const unsigned short* __restrict__ q_ws,
                                                      const unsigned short* __restrict__ k_ws,
                                                      const unsigned short* __restrict__ vT,
                                                      float* __restrict__ out) {
  __shared__ float o_sm[2][4][32][68];   // [tile][wave][q][h] padded
  __shared__ float lm_sm[2][4][32][2];

  const int wv = threadIdx.x >> 6, lane = threadIdx.x & 63;
  const int qi = lane & 31, hi = lane >> 5;
  const int hi8 = 8 * hi, hi4 = 4 * hi;

  const int bid = blockIdx.x;             // 0..511
  const int b = bid & 7;                  // batch <-> XCD alignment
  const int pr = bid >> 3;                // 0..63
  const int tiA = pr, tiB = 127 - pr;     // paired long/short 32-row tiles
  const int t0A = tiA * 32, t0B = tiB * 32;

  const unsigned short* kptr = k_ws + (size_t)b * TS * HS;
  const unsigned short* vptr = vT + (size_t)b * HS * TS;
  const unsigned short* qrA = q_ws + (size_t)(b * TS + t0A + qi) * HS + hi8;
  const unsigned short* qrB = q_ws + (size_t)(b * TS + t0B + qi) * HS + hi8;

  s16x8 qfA[4], qfB[4];
#pragma unroll
  for (int kk = 0; kk < 4; ++kk) {
    qfA[kk] = *(const s16x8*)(qrA + 16 * kk);
    qfB[kk] = *(const s16x8*)(qrB + 16 * kk);
  }

  f32x16 oA[2], oB[2];
#pragma unroll
  for (int r = 0; r < 16; ++r) { oA[0][r] = 0.f; oA[1][r] = 0.f; oB[0][r] = 0.f; oB[1][r] = 0.f; }
  float mA = -1e30f, lA = 0.f, mB = -1e30f, lB = 0.f;

  const int ntA = tiA + 1, ntB = tiB + 1;
  for (int it = wv; it < ntB; it += 4) {
    const int s0 = it * 32;
    if (it < ntA) TILE32(s0, it == tiA, qfA, mA, lA, oA)
    TILE32(s0, it == tiB, qfB, mB, lB, oB)
  }

  // ---- partials to LDS ----
#pragma unroll
  for (int ht = 0; ht < 2; ++ht)
#pragma unroll
    for (int r = 0; r < 16; ++r) {
      const int h = ht * 32 + (r & 3) + 8 * (r >> 2) + hi4;
      o_sm[0][wv][qi][h] = oA[ht][r];
      o_sm[1][wv][qi][h] = oB[ht][r];
    }
  if (lane < 32) {
    lm_sm[0][wv][lane][0] = mA; lm_sm[0][wv][lane][1] = lA;
    lm_sm[1][wv][lane][0] = mB; lm_sm[1][wv][lane][1] = lB;
  }
  __syncthreads();

  // ---- merge 4 partials per tile; thread owns (q, 8 h) ----
  const int q = threadIdx.x >> 3;         // 0..31
  const int h0 = (threadIdx.x & 7) * 8;   // 0..56
  const int t0X[2] = {t0A, t0B};
#pragma unroll
  for (int X = 0; X < 2; ++X) {
    const float m0v = lm_sm[X][0][q][0], m1v = lm_sm[X][1][q][0];
    const float m2v = lm_sm[X][2][q][0], m3v = lm_sm[X][3][q][0];
    const float M = fmaxf(fmaxf(m0v, m1v), fmaxf(m2v, m3v));
    const float w0 = __builtin_amdgcn_exp2f(m0v - M);
    const float w1 = __builtin_amdgcn_exp2f(m1v - M);
    const float w2 = __builtin_amdgcn_exp2f(m2v - M);
    const float w3 = __builtin_amdgcn_exp2f(m3v - M);
    const float L = w0 * lm_sm[X][0][q][1] + w1 * lm_sm[X][1][q][1] +
                    w2 * lm_sm[X][2][q][1] + w3 * lm_sm[X][3][q][1];
    const float inv = 1.0f / L;
    float rv[8];
#pragma unroll
    for (int j = 0; j < 8; ++j)
      rv[j] = (w0 * o_sm[X][0][q][h0 + j] + w1 * o_sm[X][1][q][h0 + j] +
               w2 * o_sm[X][2][q][h0 + j] + w3 * o_sm[X][3][q][h0 + j]) * inv;
    float* ob = out + ((size_t)(b * TS + t0X[X] + q)) * HS + h0;
    *(float4*)(ob)     = float4{rv[0], rv[1], rv[2], rv[3]};
    *(float4*)(ob + 4) = float4{rv[4], rv[5], rv[6], rv[7]};
  }
}

extern "C" void kernel_launch(void* const* d_in, const int* in_sizes, int n_in,
                              void* d_out, int out_size, void* d_ws, size_t ws_size,
                              hipStream_t stream) {
  const float* x  = (const float*)d_in[0];
  const float* Wk = (const float*)d_in[1];
  const float* Wq = (const float*)d_in[2];
  const float* Wv = (const float*)d_in[3];
  float* out = (float*)d_out;

  unsigned short* wT2  = (unsigned short*)d_ws;
  unsigned short* q_ws = wT2 + 192 * 1024;
  unsigned short* k_ws = q_ws + (size_t)NROW * HS;
  unsigned short* vT   = k_ws + (size_t)NROW * HS;

  wt_kernel<<<dim3(768), dim3(256), 0, stream>>>(Wk, Wq, Wv, wT2);
  qkv_kernel<<<dim3(512), dim3(512), 0, stream>>>(x, wT2, q_ws, k_ws, vT);
  attn_kernel<<<dim3(512), dim3(256), 0, stream>>>(q_ws, k_ws, vT, out);
}

// Round 16
// 97.777 us; speedup vs baseline: 1.3782x; 1.0272x over previous
//
#include <hip/hip_runtime.h>
#include <hip/hip_bf16.h>

// Head: k/q/v projection + causal softmax attention, single head.
// B=8, T=4096, C=1024, H=64. All inputs fp32; output fp32.
//   k0: wT2 = [Wq|Wk|Wv]^T per-chunk staged layout: chunk c (K 32c..32c+31)
//       is a contiguous 12KB image of 768 slots x 16B, slot sk=g*192+n =
//       wT[n][c*32+8g..+7] (q cols pre-scaled by 0.125*log2e).
//   k1: qkv v7: QUAD-buffered (prefetch distance 3) global_load_lds pipeline,
//       vmcnt(10), no K-split (no merge), 32 phases of K=32, 4 waves x 16
//       rows, 80KB LDS = 2 blocks/CU. R15 theory: v6's depth-2 pipeline
//       equilibrated at phase ~ latency/2 under loaded-HBM latency; depth 3
//       decouples.
//   k2: flash attention (R8-verified): 32x32x16 swapped-operand, lane-local
//       softmax, shfl_xor(32) exchanges, paired (ti,127-ti) tiles, 4-way KV
//       split, LDS merge.

#define HS 64
#define NE 1024
#define NB 8
#define TS 4096
#define NROW (NB * TS)  // 32768

#define QKV_BUF 20480   // per buffer: 12288 W + 8192 X
#define QKV_XB  12288

typedef __attribute__((ext_vector_type(4)))  float f32x4;
typedef __attribute__((ext_vector_type(16))) float f32x16;
typedef __attribute__((ext_vector_type(8)))  short s16x8;   // bf16x8 MFMA fragment
typedef __attribute__((ext_vector_type(4)))  float vfloat4;

__device__ __forceinline__ unsigned short f2bf(float x) {
  return __builtin_bit_cast(unsigned short, __float2bfloat16(x));
}
__device__ __forceinline__ unsigned pkbf(float lo, float hi) {
  return (unsigned)f2bf(lo) | ((unsigned)f2bf(hi) << 16);
}

union ABFrag { s16x8 v; unsigned d[4]; };

__device__ __forceinline__ void gl_lds16(const void* g, const unsigned char* l) {
  __builtin_amdgcn_global_load_lds(
      (const __attribute__((address_space(1))) unsigned int*)(g),
      (__attribute__((address_space(3))) unsigned int*)(l), 16, 0, 0);
}

// ---------------- kernel 0: weight transpose+cast, per-chunk layout ----
__global__ __launch_bounds__(256) void wt_kernel(const float* __restrict__ Wk,
                                                 const float* __restrict__ Wq,
                                                 const float* __restrict__ Wv,
                                                 unsigned short* __restrict__ wT2) {
  int gid = blockIdx.x * 256 + threadIdx.x;   // 0..196607
  int j = gid & 7;
  int t1 = gid >> 3;          // 0..24575
  int sk = t1 % 768;
  int c  = t1 / 768;          // 0..31
  int g = sk / 192, n = sk % 192;
  int k = c * 32 + g * 8 + j;
  const float* W = (n < 64) ? Wq : (n < 128) ? Wk : Wv;
  float s = (n < 64) ? 0.18033688011112042f : 1.0f;  // 0.125 * log2(e)
  wT2[gid] = f2bf(W[k * 64 + (n & 63)] * s);
}

// ---------------- kernel 1: fused QKV projection v7 ----------------
// Block 256 thd = 4 waves, 64 rows (16/wave), all 192 cols. 32 phases, K=32.
// Per phase c:
//   W: wave w stages slots w*192..+191 of chunk c: 3 gl_lds of contiguous
//      1KB from wT2 + c*6144 (ushorts).
//   X: wave w stages its rows w*16..+15, row-major [row][128B]: 2 gl_lds,
//      8-lane/128B coalesced segments; dest = XB + w*2048 (+1024).
// Quad buffer (c&3), issue c+3 after compute, vmcnt(10) (oldest 5 = cluster
// c complete) then barrier (covers other waves' staging). Tail: 10/5/0.
__global__ __launch_bounds__(256, 2) void qkv_kernel(const float* __restrict__ x,
                                                     const unsigned short* __restrict__ wT2,
                                                     unsigned short* __restrict__ q_ws,
                                                     unsigned short* __restrict__ k_ws,
                                                     unsigned short* __restrict__ vT) {
  __shared__ __align__(16) unsigned char smem[4 * QKV_BUF];  // 81920 B
  const int t = threadIdx.x;
  const int w = t >> 6, lane = t & 63;
  const int g = lane >> 4, nn = lane & 15;
  const int m0blk = blockIdx.x * 64;
  const int m0 = m0blk + w * 16;

  f32x4 acc[12];
#pragma unroll
  for (int i = 0; i < 12; ++i) acc[i] = f32x4{0.f, 0.f, 0.f, 0.f};

  // ---- staging sources ----
  const unsigned short* wsrcA = wT2 + (size_t)(w * 192 + lane) * 8;  // +c*6144
  const int wd0 = w * 3072;                                          // +p*1024
  const float* xs0 = x + (size_t)(m0blk + w * 16 + 0 + (lane >> 3)) * NE + (lane & 7) * 4;
  const float* xs1 = x + (size_t)(m0blk + w * 16 + 8 + (lane >> 3)) * NE + (lane & 7) * 4;
  const int xd0 = QKV_XB + w * 2048;
  const int xd1 = xd0 + 1024;

  // ---- read offsets ----
  const int abase = QKV_XB + (w * 16 + nn) * 128 + g * 32;
  const int wbase = (g * 192 + nn) * 16;

#define ISSUE(C)                                                               \
  {                                                                            \
    unsigned char* db_ = smem + ((C) & 3) * QKV_BUF;                           \
    gl_lds16(wsrcA + (size_t)(C) * 6144, db_ + wd0);                           \
    gl_lds16(wsrcA + (size_t)(C) * 6144 + 512, db_ + wd0 + 1024);              \
    gl_lds16(wsrcA + (size_t)(C) * 6144 + 1024, db_ + wd0 + 2048);             \
    gl_lds16(xs0 + (C) * 32, db_ + xd0);                                       \
    gl_lds16(xs1 + (C) * 32, db_ + xd1);                                       \
  }

  // ---- prologue: clusters 0,1,2 in order ----
  ISSUE(0)
  __builtin_amdgcn_sched_barrier(0);
  ISSUE(1)
  __builtin_amdgcn_sched_barrier(0);
  ISSUE(2)
  __builtin_amdgcn_sched_barrier(0);

#define PHASE(C, VM, DOISS)                                                    \
  {                                                                            \
    asm volatile("s_waitcnt vmcnt(" #VM ")" ::: "memory");                     \
    __builtin_amdgcn_s_barrier();                                              \
    __builtin_amdgcn_sched_barrier(0);                                         \
    const unsigned char* bb_ = smem + ((C) & 3) * QKV_BUF;                     \
    const vfloat4 a0_ = *(const vfloat4*)(bb_ + abase);                        \
    const vfloat4 a1_ = *(const vfloat4*)(bb_ + abase + 16);                   \
    ABFrag af;                                                                 \
    af.d[0] = pkbf(a0_.x, a0_.y); af.d[1] = pkbf(a0_.z, a0_.w);                \
    af.d[2] = pkbf(a1_.x, a1_.y); af.d[3] = pkbf(a1_.z, a1_.w);                \
    _Pragma("unroll")                                                          \
    for (int i = 0; i < 12; ++i) {                                             \
      const s16x8 bf = *(const s16x8*)(bb_ + wbase + i * 256);                 \
      acc[i] = __builtin_amdgcn_mfma_f32_16x16x32_bf16(af.v, bf, acc[i], 0, 0, 0); \
    }                                                                          \
    __builtin_amdgcn_sched_barrier(0);                                         \
    __builtin_amdgcn_s_barrier();                                              \
    __builtin_amdgcn_sched_barrier(0);                                         \
    if (DOISS) { ISSUE((C) + 3) }                                              \
    __builtin_amdgcn_sched_barrier(0);                                         \
  }

#pragma unroll
  for (int c = 0; c < 29; ++c) PHASE(c, 10, 1)
  PHASE(29, 10, 0)
  PHASE(30, 5, 0)
  PHASE(31, 0, 0)
#undef PHASE
#undef ISSUE

  // ---- epilogue: D row = m0 + 4g + j, col = 16i + nn ----
  const int rbase = m0 + 4 * g;
#pragma unroll
  for (int i = 0; i < 12; ++i) {
    const int c = 16 * i + nn;
#pragma unroll
    for (int j = 0; j < 4; ++j) {
      const int rr = rbase + j;
      const unsigned short h = f2bf(acc[i][j]);
      if (c < 64) {
        q_ws[(size_t)rr * HS + c] = h;
      } else if (c < 128) {
        k_ws[(size_t)rr * HS + (c - 64)] = h;
      } else {
        const int b = rr >> 12, tt = rr & 4095;
        vT[((size_t)(b * HS + (c - 128))) * TS + tt] = h;
      }
    }
  }
}

// ---------------- kernel 2: causal flash attention, 32x32 lane-local -------
// S^T(32kv x 32q) = sum_kk mfma32x32x16(K-frag, Q^T-frag). Lane (qi,hi) holds
// st_[r] = S^T[kv=(r&3)+8*(r>>2)+4hi][q=qi]; the other 16 kv live in lane^32.
// Reduces and P^T B-frag assembly use __shfl_xor(...,32).
#define TILE32(S0, DIAG, QF, M_RUN, L_RUN, O)                                  \
  {                                                                            \
    const int s0_ = (S0);                                                      \
    const unsigned short* kr_ = kptr + (size_t)(s0_ + qi) * HS + hi8;          \
    const s16x8 ka0_ = *(const s16x8*)(kr_);                                   \
    const s16x8 ka1_ = *(const s16x8*)(kr_ + 16);                              \
    const s16x8 ka2_ = *(const s16x8*)(kr_ + 32);                              \
    const s16x8 ka3_ = *(const s16x8*)(kr_ + 48);                              \
    const unsigned short* vr0_ = vptr + (size_t)qi * TS + s0_ + hi8;           \
    const unsigned short* vr1_ = vptr + (size_t)(32 + qi) * TS + s0_ + hi8;    \
    f32x16 st_;                                                                \
    _Pragma("unroll") for (int r = 0; r < 16; ++r) st_[r] = 0.f;               \
    st_ = __builtin_amdgcn_mfma_f32_32x32x16_bf16(ka0_, QF[0], st_, 0, 0, 0);  \
    st_ = __builtin_amdgcn_mfma_f32_32x32x16_bf16(ka1_, QF[1], st_, 0, 0, 0);  \
    st_ = __builtin_amdgcn_mfma_f32_32x32x16_bf16(ka2_, QF[2], st_, 0, 0, 0);  \
    st_ = __builtin_amdgcn_mfma_f32_32x32x16_bf16(ka3_, QF[3], st_, 0, 0, 0);  \
    if (DIAG) {                                                                \
      _Pragma("unroll") for (int r = 0; r < 16; ++r) {                         \
        const int kvl_ = (r & 3) + 8 * (r >> 2) + hi4;                         \
        if (kvl_ > qi) st_[r] = -1e30f;                                        \
      }                                                                        \
    }                                                                          \
    float mx_ =                                                                \
      fmaxf(fmaxf(fmaxf(fmaxf(st_[0], st_[1]), fmaxf(st_[2], st_[3])),         \
                  fmaxf(fmaxf(st_[4], st_[5]), fmaxf(st_[6], st_[7]))),        \
            fmaxf(fmaxf(fmaxf(st_[8], st_[9]), fmaxf(st_[10], st_[11])),       \
                  fmaxf(fmaxf(st_[12], st_[13]), fmaxf(st_[14], st_[15]))));   \
    mx_ = fmaxf(mx_, __shfl_xor(mx_, 32, 64));                                 \
    const float mn_ = fmaxf(M_RUN, mx_);                                       \
    if (__ballot(mn_ > M_RUN)) {                                               \
      const float fs_ = __builtin_amdgcn_exp2f(M_RUN - mn_);                   \
      _Pragma("unroll") for (int r = 0; r < 16; ++r) {                         \
        O[0][r] *= fs_; O[1][r] *= fs_;                                        \
      }                                                                        \
      L_RUN *= fs_;                                                            \
      M_RUN = mn_;                                                             \
    }                                                                          \
    float p_[16];                                                              \
    _Pragma("unroll") for (int r = 0; r < 16; ++r)                             \
      p_[r] = __builtin_amdgcn_exp2f(st_[r] - M_RUN);                          \
    float sm_ = ((p_[0] + p_[1]) + (p_[2] + p_[3])) +                          \
                ((p_[4] + p_[5]) + (p_[6] + p_[7]));                           \
    sm_ += ((p_[8] + p_[9]) + (p_[10] + p_[11])) +                             \
           ((p_[12] + p_[13]) + (p_[14] + p_[15]));                            \
    sm_ += __shfl_xor(sm_, 32, 64);                                            \
    L_RUN += sm_;                                                              \
    const unsigned q01_ = pkbf(p_[0], p_[1]),   q23_ = pkbf(p_[2], p_[3]);     \
    const unsigned q45_ = pkbf(p_[4], p_[5]),   q67_ = pkbf(p_[6], p_[7]);     \
    const unsigned q89_ = pkbf(p_[8], p_[9]),   qab_ = pkbf(p_[10], p_[11]);   \
    const unsigned qcd_ = pkbf(p_[12], p_[13]), qef_ = pkbf(p_[14], p_[15]);   \
    const unsigned t01_ = (unsigned)__shfl_xor((int)q01_, 32, 64);             \
    const unsigned t23_ = (unsigned)__shfl_xor((int)q23_, 32, 64);             \
    const unsigned t45_ = (unsigned)__shfl_xor((int)q45_, 32, 64);             \
    const unsigned t67_ = (unsigned)__shfl_xor((int)q67_, 32, 64);             \
    const unsigned t89_ = (unsigned)__shfl_xor((int)q89_, 32, 64);             \
    const unsigned tab_ = (unsigned)__shfl_xor((int)qab_, 32, 64);             \
    const unsigned tcd_ = (unsigned)__shfl_xor((int)qcd_, 32, 64);             \
    const unsigned tef_ = (unsigned)__shfl_xor((int)qef_, 32, 64);             \
    ABFrag pf0_, pf1_;                                                         \
    pf0_.d[0] = hi ? t45_ : q01_;                                              \
    pf0_.d[1] = hi ? t67_ : q23_;                                              \
    pf0_.d[2] = hi ? q45_ : t01_;                                              \
    pf0_.d[3] = hi ? q67_ : t23_;                                              \
    pf1_.d[0] = hi ? tcd_ : q89_;                                              \
    pf1_.d[1] = hi ? tef_ : qab_;                                              \
    pf1_.d[2] = hi ? qcd_ : t89_;                                              \
    pf1_.d[3] = hi ? qef_ : tab_;                                              \
    const s16x8 vf00_ = *(const s16x8*)(vr0_);                                 \
    const s16x8 vf01_ = *(const s16x8*)(vr0_ + 16);                            \
    const s16x8 vf10_ = *(const s16x8*)(vr1_);                                 \
    const s16x8 vf11_ = *(const s16x8*)(vr1_ + 16);                            \
    O[0] = __builtin_amdgcn_mfma_f32_32x32x16_bf16(vf00_, pf0_.v, O[0], 0,0,0);\
    O[0] = __builtin_amdgcn_mfma_f32_32x32x16_bf16(vf01_, pf1_.v, O[0], 0,0,0);\
    O[1] = __builtin_amdgcn_mfma_f32_32x32x16_bf16(vf10_, pf0_.v, O[1], 0,0,0);\
    O[1] = __builtin_amdgcn_mfma_f32_32x32x16_bf16(vf11_, pf1_.v, O[1], 0,0,0);\
  }

__global__ __launch_bounds__(256, 2) void attn_kernel(const unsigned short* __restrict__ q_ws,
                                                      const unsigned short* __restrict__ k_ws,
                                                      const unsigned short* __restrict__ vT,
                                                      float* __restrict__ out) {
  __shared__ float o_sm[2][4][32][68];   // [tile][wave][q][h] padded
  __shared__ float lm_sm[2][4][32][2];

  const int wv = threadIdx.x >> 6, lane = threadIdx.x & 63;
  const int qi = lane & 31, hi = lane >> 5;
  const int hi8 = 8 * hi, hi4 = 4 * hi;

  const int bid = blockIdx.x;             // 0..511
  const int b = bid & 7;                  // batch <-> XCD alignment
  const int pr = bid >> 3;                // 0..63
  const int tiA = pr, tiB = 127 - pr;     // paired long/short 32-row tiles
  const int t0A = tiA * 32, t0B = tiB * 32;

  const unsigned short* kptr = k_ws + (size_t)b * TS * HS;
  const unsigned short* vptr = vT + (size_t)b * HS * TS;
  const unsigned short* qrA = q_ws + (size_t)(b * TS + t0A + qi) * HS + hi8;
  const unsigned short* qrB = q_ws + (size_t)(b * TS + t0B + qi) * HS + hi8;

  s16x8 qfA[4], qfB[4];
#pragma unroll
  for (int kk = 0; kk < 4; ++kk) {
    qfA[kk] = *(const s16x8*)(qrA + 16 * kk);
    qfB[kk] = *(const s16x8*)(qrB + 16 * kk);
  }

  f32x16 oA[2], oB[2];
#pragma unroll
  for (int r = 0; r < 16; ++r) { oA[0][r] = 0.f; oA[1][r] = 0.f; oB[0][r] = 0.f; oB[1][r] = 0.f; }
  float mA = -1e30f, lA = 0.f, mB = -1e30f, lB = 0.f;

  const int ntA = tiA + 1, ntB = tiB + 1;
  for (int it = wv; it < ntB; it += 4) {
    const int s0 = it * 32;
    if (it < ntA) TILE32(s0, it == tiA, qfA, mA, lA, oA)
    TILE32(s0, it == tiB, qfB, mB, lB, oB)
  }

  // ---- partials to LDS ----
#pragma unroll
  for (int ht = 0; ht < 2; ++ht)
#pragma unroll
    for (int r = 0; r < 16; ++r) {
      const int h = ht * 32 + (r & 3) + 8 * (r >> 2) + hi4;
      o_sm[0][wv][qi][h] = oA[ht][r];
      o_sm[1][wv][qi][h] = oB[ht][r];
    }
  if (lane < 32) {
    lm_sm[0][wv][lane][0] = mA; lm_sm[0][wv][lane][1] = lA;
    lm_sm[1][wv][lane][0] = mB; lm_sm[1][wv][lane][1] = lB;
  }
  __syncthreads();

  // ---- merge 4 partials per tile; thread owns (q, 8 h) ----
  const int q = threadIdx.x >> 3;         // 0..31
  const int h0 = (threadIdx.x & 7) * 8;   // 0..56
  const int t0X[2] = {t0A, t0B};
#pragma unroll
  for (int X = 0; X < 2; ++X) {
    const float m0v = lm_sm[X][0][q][0], m1v = lm_sm[X][1][q][0];
    const float m2v = lm_sm[X][2][q][0], m3v = lm_sm[X][3][q][0];
    const float M = fmaxf(fmaxf(m0v, m1v), fmaxf(m2v, m3v));
    const float w0 = __builtin_amdgcn_exp2f(m0v - M);
    const float w1 = __builtin_amdgcn_exp2f(m1v - M);
    const float w2 = __builtin_amdgcn_exp2f(m2v - M);
    const float w3 = __builtin_amdgcn_exp2f(m3v - M);
    const float L = w0 * lm_sm[X][0][q][1] + w1 * lm_sm[X][1][q][1] +
                    w2 * lm_sm[X][2][q][1] + w3 * lm_sm[X][3][q][1];
    const float inv = 1.0f / L;
    float rv[8];
#pragma unroll
    for (int j = 0; j < 8; ++j)
      rv[j] = (w0 * o_sm[X][0][q][h0 + j] + w1 * o_sm[X][1][q][h0 + j] +
               w2 * o_sm[X][2][q][h0 + j] + w3 * o_sm[X][3][q][h0 + j]) * inv;
    float* ob = out + ((size_t)(b * TS + t0X[X] + q)) * HS + h0;
    *(float4*)(ob)     = float4{rv[0], rv[1], rv[2], rv[3]};
    *(float4*)(ob + 4) = float4{rv[4], rv[5], rv[6], rv[7]};
  }
}

extern "C" void kernel_launch(void* const* d_in, const int* in_sizes, int n_in,
                              void* d_out, int out_size, void* d_ws, size_t ws_size,
                              hipStream_t stream) {
  const float* x  = (const float*)d_in[0];
  const float* Wk = (const float*)d_in[1];
  const float* Wq = (const float*)d_in[2];
  const float* Wv = (const float*)d_in[3];
  float* out = (float*)d_out;

  unsigned short* wT2  = (unsigned short*)d_ws;
  unsigned short* q_ws = wT2 + 192 * 1024;
  unsigned short* k_ws = q_ws + (size_t)NROW * HS;
  unsigned short* vT   = k_ws + (size_t)NROW * HS;

  wt_kernel<<<dim3(768), dim3(256), 0, stream>>>(Wk, Wq, Wv, wT2);
  qkv_kernel<<<dim3(NROW / 64), dim3(256), 0, stream>>>(x, wT2, q_ws, k_ws, vT);
  attn_kernel<<<dim3(512), dim3(256), 0, stream>>>(q_ws, k_ws, vT, out);
}